// Round 4
// baseline (716.397 us; speedup 1.0000x reference)
//
#include <hip/hip_runtime.h>
#include <math.h>

namespace {

constexpr int NN = 50000;
constexpr int EE = 400000;
constexpr int CIN = 512;
constexpr int GH = 128;
constexpr int GO = 64;
constexpr int HEADS = 4;
constexpr int COUT = 32;
constexpr float EPS = 1e-5f;

typedef __attribute__((ext_vector_type(8))) short short8;
typedef __attribute__((ext_vector_type(4))) float f32x4;
typedef __attribute__((ext_vector_type(4))) unsigned int uint4v;

inline int cdiv(int a, int b) { return (a + b - 1) / b; }

__device__ __forceinline__ void split2(float x, unsigned short& hi, unsigned short& lo) {
  unsigned b = __float_as_uint(x);
  hi = (unsigned short)(b >> 16);
  float hf = __uint_as_float(b & 0xFFFF0000u);
  lo = (unsigned short)(__float_as_uint(x - hf) >> 16);
}

// ---- init ---------------------------------------------------------------
__global__ void k_init0(float* deg, int* cnt, int* cur, int* bins) {
  int i = blockIdx.x * blockDim.x + threadIdx.x;
  if (i < NN) { deg[i] = 0.0f; cnt[i] = 0; cur[i] = 0; }
  if (i < 64) bins[i] = 0;
}

__global__ void k_edge1(const int* __restrict__ ei, const float* __restrict__ w,
                        float* __restrict__ deg, int* __restrict__ cnt) {
  int e = blockIdx.x * blockDim.x + threadIdx.x;
  if (e < EE) {
    int d = ei[EE + e];
    atomicAdd(&deg[d], w[e]);
    atomicAdd(&cnt[d], 1);
  }
}

__global__ void k_dinv(float* deg) {
  int i = blockIdx.x * blockDim.x + threadIdx.x;
  if (i < NN) deg[i] = rsqrtf(deg[i] + 1.0f);
}

// ---- degree histogram / scan / permutation (counting sort by degree) ----
__global__ void k_hist(const int* __restrict__ cnt, int* __restrict__ bins) {
  int i = blockIdx.x * blockDim.x + threadIdx.x;
  if (i < NN) atomicAdd(&bins[min(cnt[i], 63)], 1);
}

__global__ void k_binscan(const int* __restrict__ bins, int* __restrict__ cursor) {
  int l = threadIdx.x;  // 64 threads
  int v = bins[l];
  int x = v;
#pragma unroll
  for (int s = 1; s < 64; s <<= 1) {
    int t = __shfl_up(x, s);
    if (l >= s) x += t;
  }
  cursor[l] = x - v;  // exclusive
}

__global__ void k_perm(const int* __restrict__ cnt, int* __restrict__ cursor,
                       int* __restrict__ perm) {
  int i = blockIdx.x * blockDim.x + threadIdx.x;
  if (i < NN) {
    int b = min(cnt[i], 63);
    int pos = atomicAdd(&cursor[b], 1);
    perm[pos] = i;
  }
}

// ---- exclusive scan of cnt[NN] -> ro, single block ----------------------
__launch_bounds__(1024) __global__ void k_scan(const int* __restrict__ cnt,
                                               int* __restrict__ ro) {
  __shared__ int wsum[16];
  __shared__ int carry_s;
  const int tid = threadIdx.x;
  const int lane = tid & 63;
  const int wv = tid >> 6;
  if (tid == 0) carry_s = 0;
  __syncthreads();
  for (int base = 0; base < NN; base += 1024) {
    int idx = base + tid;
    int v = idx < NN ? cnt[idx] : 0;
    int x = v;
#pragma unroll
    for (int s = 1; s < 64; s <<= 1) {
      int t = __shfl_up(x, s);
      if (lane >= s) x += t;
    }
    if (lane == 63) wsum[wv] = x;
    __syncthreads();
    if (wv == 0 && lane < 16) {
      int wsc = wsum[lane];
#pragma unroll
      for (int s = 1; s < 16; s <<= 1) {
        int t = __shfl_up(wsc, s);
        if (lane >= s) wsc += t;
      }
      wsum[lane] = wsc;
    }
    __syncthreads();
    int waveoff = (wv == 0) ? 0 : wsum[wv - 1];
    int carry = carry_s;
    if (idx < NN) ro[idx] = carry + waveoff + x - v;
    __syncthreads();
    if (tid == 1023) carry_s = carry + wsum[15];
    __syncthreads();
  }
  if (threadIdx.x == 0) ro[NN] = carry_s;
}

__global__ void k_fill(const int* __restrict__ ei, const float* __restrict__ w,
                       const float* __restrict__ dinv, const int* __restrict__ ro,
                       int* __restrict__ cur, int* __restrict__ csr_src,
                       float* __restrict__ csr_nrm) {
  int e = blockIdx.x * blockDim.x + threadIdx.x;
  if (e >= EE) return;
  int s = ei[e], d = ei[EE + e];
  int p = ro[d] + atomicAdd(&cur[d], 1);
  csr_src[p] = s;
  csr_nrm[p] = dinv[s] * w[e] * dinv[d];
}

// ---- B-matrix hi/lo split + transpose -----------------------------------
__global__ void k_split(const float* __restrict__ B, unsigned short* __restrict__ Bp,
                        int K, int F) {
  int idx = blockIdx.x * blockDim.x + threadIdx.x;
  if (idx >= K * F) return;
  int k = idx / F, f = idx - k * F;
  unsigned short hi, lo;
  split2(B[idx], hi, lo);
  Bp[f * K + k] = hi;
  Bp[(size_t)F * K + f * K + k] = lo;
}

// ---- MFMA GEMM (unchanged from round 3) ---------------------------------
template <int BN, bool ACC, bool BNR>
__launch_bounds__(256, 2) __global__
void mgemm(const float* __restrict__ A, const unsigned short* __restrict__ Bp,
           const float* __restrict__ bias, float* __restrict__ C,
           int M, int K, int F,
           const float* __restrict__ bn_g, const float* __restrict__ bn_b,
           const float* __restrict__ bn_m, const float* __restrict__ bn_v) {
  constexpr int BM = 64;
  constexpr int BK = 64;
  constexpr int NR = BN / 32;

  __shared__ unsigned short lds[(BM + BN) * BK * 2];
  unsigned short* Ah = lds;
  unsigned short* Al = Ah + BM * BK;
  unsigned short* Bh = Al + BM * BK;
  unsigned short* Bl = Bh + BN * BK;

  const int tid = threadIdx.x;
  const int lane = tid & 63;
  const int wid = tid >> 6;
  const int wr = wid >> 1, wc = wid & 1;
  const int l15 = lane & 15, lhi = lane >> 4;
  const int m0 = blockIdx.x * BM;
  const int n0 = blockIdx.y * BN;

  f32x4 acc[2][NR];
#pragma unroll
  for (int mi = 0; mi < 2; ++mi)
#pragma unroll
    for (int ni = 0; ni < NR; ++ni) acc[mi][ni] = (f32x4)0.0f;

  for (int k0 = 0; k0 < K; k0 += BK) {
    {
      const int r = tid >> 2, ch = tid & 3;
      const int gr = m0 + r;
      float xv[16];
      if (gr < M) {
        const float4* src =
            reinterpret_cast<const float4*>(A + (size_t)gr * K + k0 + ch * 16);
#pragma unroll
        for (int i = 0; i < 4; ++i) {
          float4 f = src[i];
          xv[i * 4 + 0] = f.x; xv[i * 4 + 1] = f.y;
          xv[i * 4 + 2] = f.z; xv[i * 4 + 3] = f.w;
        }
      } else {
#pragma unroll
        for (int i = 0; i < 16; ++i) xv[i] = 0.0f;
      }
      short8 vh0, vl0, vh1, vl1;
#pragma unroll
      for (int i = 0; i < 8; ++i) {
        unsigned short h, l;
        split2(xv[i], h, l);
        vh0[i] = (short)h; vl0[i] = (short)l;
      }
#pragma unroll
      for (int i = 0; i < 8; ++i) {
        unsigned short h, l;
        split2(xv[8 + i], h, l);
        vh1[i] = (short)h; vl1[i] = (short)l;
      }
      const int base = r * 128 + ch * 32;
      const int sw = (r & 7) << 4;
      *reinterpret_cast<short8*>((char*)Ah + (base ^ sw)) = vh0;
      *reinterpret_cast<short8*>((char*)Ah + ((base + 16) ^ sw)) = vh1;
      *reinterpret_cast<short8*>((char*)Al + (base ^ sw)) = vl0;
      *reinterpret_cast<short8*>((char*)Al + ((base + 16) ^ sw)) = vl1;
    }
    {
#pragma unroll
      for (int it = 0; it < BN / 16; ++it) {
        int id = tid + it * 256;
        int kc = id & 7;
        int colp = id >> 3;
        int col = colp & (BN - 1);
        int plane = colp >> (BN == 32 ? 5 : (BN == 64 ? 6 : 7));
        const uint4v gv = *reinterpret_cast<const uint4v*>(
            Bp + ((size_t)plane * F + n0 + col) * K + k0 + kc * 8);
        unsigned short* dst = plane ? Bl : Bh;
        const int base = col * 128 + kc * 16;
        *reinterpret_cast<uint4v*>((char*)dst + (base ^ ((col & 7) << 4))) = gv;
      }
    }
    __syncthreads();

#pragma unroll
    for (int ks = 0; ks < 2; ++ks) {
      short8 ahf[2], alf[2], bhf[NR], blf[NR];
#pragma unroll
      for (int mi = 0; mi < 2; ++mi) {
        int row = wr * 32 + mi * 16 + l15;
        int off = (row * 128 + (ks * 32 + lhi * 8) * 2) ^ ((row & 7) << 4);
        ahf[mi] = *reinterpret_cast<const short8*>((const char*)Ah + off);
        alf[mi] = *reinterpret_cast<const short8*>((const char*)Al + off);
      }
#pragma unroll
      for (int ni = 0; ni < NR; ++ni) {
        int col = wc * (BN / 2) + ni * 16 + l15;
        int off = (col * 128 + (ks * 32 + lhi * 8) * 2) ^ ((col & 7) << 4);
        bhf[ni] = *reinterpret_cast<const short8*>((const char*)Bh + off);
        blf[ni] = *reinterpret_cast<const short8*>((const char*)Bl + off);
      }
#pragma unroll
      for (int mi = 0; mi < 2; ++mi)
#pragma unroll
        for (int ni = 0; ni < NR; ++ni) {
          acc[mi][ni] = __builtin_amdgcn_mfma_f32_16x16x32_bf16(
              ahf[mi], bhf[ni], acc[mi][ni], 0, 0, 0);
          acc[mi][ni] = __builtin_amdgcn_mfma_f32_16x16x32_bf16(
              ahf[mi], blf[ni], acc[mi][ni], 0, 0, 0);
          acc[mi][ni] = __builtin_amdgcn_mfma_f32_16x16x32_bf16(
              alf[mi], bhf[ni], acc[mi][ni], 0, 0, 0);
        }
    }
    __syncthreads();
  }

#pragma unroll
  for (int mi = 0; mi < 2; ++mi) {
#pragma unroll
    for (int ni = 0; ni < NR; ++ni) {
      const int col = n0 + wc * (BN / 2) + ni * 16 + l15;
      const float bv = bias ? bias[col] : 0.0f;
      float bns = 0.f, bnb = 0.f, bnm = 0.f;
      if (BNR) {
        bns = bn_g[col] * rsqrtf(bn_v[col] + EPS);
        bnb = bn_b[col];
        bnm = bn_m[col];
      }
#pragma unroll
      for (int r4 = 0; r4 < 4; ++r4) {
        const int row = m0 + wr * 32 + mi * 16 + lhi * 4 + r4;
        if (row < M) {
          float vout = acc[mi][ni][r4] + bv;
          if (ACC) vout += C[(size_t)row * F + col];
          if (BNR) {
            vout = (vout - bnm) * bns + bnb;
            vout = vout > 0.f ? vout : 0.f;
          }
          C[(size_t)row * F + col] = vout;
        }
      }
    }
  }
}

// ---- GCN propagate (CSR gather) + BN + ReLU, wave per dst, unroll 4 -----
template <int F>
__launch_bounds__(256) __global__
void k_gcn(const int* __restrict__ ro, const int* __restrict__ csr_src,
           const float* __restrict__ csr_nrm, const float* __restrict__ h,
           const float* __restrict__ dinv, const float* __restrict__ bias,
           const float* __restrict__ g, const float* __restrict__ be,
           const float* __restrict__ m, const float* __restrict__ v,
           float* __restrict__ out) {
  const int wid = blockIdx.x * 4 + (threadIdx.x >> 6);
  const int lane = threadIdx.x & 63;
  if (wid >= NN) return;
  const float di = dinv[wid];
  const float di2 = di * di;
  const int p0 = ro[wid], p1 = ro[wid + 1];

  if (F == 128) {
    float2 a0 = reinterpret_cast<const float2*>(h + (size_t)wid * 128)[lane];
    a0.x *= di2; a0.y *= di2;
    float2 a1 = make_float2(0.f, 0.f), a2 = make_float2(0.f, 0.f),
           a3 = make_float2(0.f, 0.f);
    int p = p0;
    for (; p + 4 <= p1; p += 4) {
      int s0 = csr_src[p], s1 = csr_src[p + 1], s2 = csr_src[p + 2],
          s3 = csr_src[p + 3];
      float w0 = csr_nrm[p], w1 = csr_nrm[p + 1], w2 = csr_nrm[p + 2],
            w3 = csr_nrm[p + 3];
      float2 h0 = reinterpret_cast<const float2*>(h + (size_t)s0 * 128)[lane];
      float2 h1 = reinterpret_cast<const float2*>(h + (size_t)s1 * 128)[lane];
      float2 h2 = reinterpret_cast<const float2*>(h + (size_t)s2 * 128)[lane];
      float2 h3 = reinterpret_cast<const float2*>(h + (size_t)s3 * 128)[lane];
      a0.x += w0 * h0.x; a0.y += w0 * h0.y;
      a1.x += w1 * h1.x; a1.y += w1 * h1.y;
      a2.x += w2 * h2.x; a2.y += w2 * h2.y;
      a3.x += w3 * h3.x; a3.y += w3 * h3.y;
    }
    for (; p < p1; ++p) {
      int s = csr_src[p];
      float w = csr_nrm[p];
      float2 hv = reinterpret_cast<const float2*>(h + (size_t)s * 128)[lane];
      a1.x += w * hv.x; a1.y += w * hv.y;
    }
    float2 a;
    a.x = (a0.x + a1.x) + (a2.x + a3.x);
    a.y = (a0.y + a1.y) + (a2.y + a3.y);
    float2 gg = reinterpret_cast<const float2*>(g)[lane];
    float2 bb = reinterpret_cast<const float2*>(be)[lane];
    float2 mm = reinterpret_cast<const float2*>(m)[lane];
    float2 vv = reinterpret_cast<const float2*>(v)[lane];
    float2 bi = bias ? reinterpret_cast<const float2*>(bias)[lane]
                     : make_float2(0.f, 0.f);
    float s0 = gg.x * rsqrtf(vv.x + EPS);
    float s1 = gg.y * rsqrtf(vv.y + EPS);
    float y0 = (a.x + bi.x - mm.x) * s0 + bb.x;
    float y1 = (a.y + bi.y - mm.y) * s1 + bb.y;
    float2 o;
    o.x = y0 > 0.f ? y0 : 0.f;
    o.y = y1 > 0.f ? y1 : 0.f;
    reinterpret_cast<float2*>(out + (size_t)wid * 128)[lane] = o;
  } else {
    float a0 = h[(size_t)wid * F + lane] * di2;
    float a1 = 0.f, a2 = 0.f, a3 = 0.f;
    int p = p0;
    for (; p + 4 <= p1; p += 4) {
      int s0 = csr_src[p], s1 = csr_src[p + 1], s2 = csr_src[p + 2],
          s3 = csr_src[p + 3];
      float w0 = csr_nrm[p], w1 = csr_nrm[p + 1], w2 = csr_nrm[p + 2],
            w3 = csr_nrm[p + 3];
      a0 += w0 * h[(size_t)s0 * F + lane];
      a1 += w1 * h[(size_t)s1 * F + lane];
      a2 += w2 * h[(size_t)s2 * F + lane];
      a3 += w3 * h[(size_t)s3 * F + lane];
    }
    for (; p < p1; ++p) a1 += csr_nrm[p] * h[(size_t)csr_src[p] * F + lane];
    float a = (a0 + a1) + (a2 + a3);
    float sc = g[lane] * rsqrtf(v[lane] + EPS);
    float bi = bias ? bias[lane] : 0.f;
    float y = (a + bi - m[lane]) * sc + be[lane];
    out[(size_t)wid * F + lane] = y > 0.f ? y : 0.f;
  }
}

// ---- attention precompute: Mc[64][256], cvec[256] -----------------------
__global__ void k_prep_mc(const float* __restrict__ Wq, const float* __restrict__ Wk,
                          const float* __restrict__ bq, float* __restrict__ Mc,
                          float* __restrict__ cvec) {
  int i = blockIdx.x;
  int col = threadIdx.x;
  int h = col >> 6, j = col & 63;
  float acc = 0.f;
  for (int t = 0; t < 64; ++t)
    acc += Wq[i * 256 + h * 64 + t] * Wk[j * 256 + h * 64 + t];
  Mc[i * 256 + col] = 0.125f * acc;
  if (i == 0) {
    float c = 0.f;
    for (int t = 0; t < 64; ++t) c += bq[h * 64 + t] * Wk[j * 256 + h * 64 + t];
    cvec[col] = 0.125f * c;
  }
}

__global__ void k_prep_bv(const float* __restrict__ Wv, const float* __restrict__ bv,
                          float* __restrict__ Bv, float* __restrict__ bvs) {
  int idx = blockIdx.x * blockDim.x + threadIdx.x;
  if (idx < 256 * 64) {
    int r = idx >> 6, t = idx & 63;
    int h = r >> 6, c = r & 63;
    Bv[idx] = 0.25f * Wv[c * 256 + h * 64 + t];
  }
  if (blockIdx.x == 0 && threadIdx.x < 64) {
    int t = threadIdx.x;
    float s = 0.f;
    for (int h = 0; h < HEADS; ++h) s += bv[h * 64 + t];
    bvs[t] = 0.25f * s;
  }
}

// ---- fused edge-softmax attention: 16 lanes per dst, 4 dsts per wave ----
// No max-shift: scores |s| << 60 here (z^T M z, |M|~2.5e-3); exp clamp at 60
// is inert insurance; softmax is shift-invariant so result is identical.
__launch_bounds__(256) __global__
void k_attn(const int* __restrict__ ro, const int* __restrict__ csr_src,
            const int* __restrict__ perm, const float* __restrict__ z,
            const float* __restrict__ qpp, float* __restrict__ u) {
  const int wave = blockIdx.x * 4 + (threadIdx.x >> 6);
  const int lane = threadIdx.x & 63;
  const int g = lane >> 4;   // dst group 0..3
  const int t = lane & 15;   // sublane
  const bool bit3 = (t & 8) != 0, bit2 = (t & 4) != 0;

  const int idx = wave * 4 + g;
  const bool valid = idx < NN;
  const int dst = perm[valid ? idx : 0];

  float4 q[4];
#pragma unroll
  for (int h = 0; h < 4; ++h)
    q[h] = *reinterpret_cast<const float4*>(qpp + (size_t)dst * 256 + h * 64 + t * 4);

  float4 ua[4];
  float den[4];
#pragma unroll
  for (int h = 0; h < 4; ++h) {
    ua[h] = make_float4(0.f, 0.f, 0.f, 0.f);
    den[h] = 0.f;
  }

  int p = valid ? ro[dst] : 0;
  int p1 = valid ? ro[dst + 1] : 0;

  while (__ballot(p < p1)) {
    const bool act = p < p1;
    const int pc = act ? p : 0;
    const int s = csr_src[pc];
    const float4 zv = *reinterpret_cast<const float4*>(z + (size_t)s * 64 + t * 4);

    // per-lane partial dots for 4 heads
    float p0 = q[0].x * zv.x + q[0].y * zv.y + q[0].z * zv.z + q[0].w * zv.w;
    float p1h = q[1].x * zv.x + q[1].y * zv.y + q[1].z * zv.z + q[1].w * zv.w;
    float p2 = q[2].x * zv.x + q[2].y * zv.y + q[2].z * zv.z + q[2].w * zv.w;
    float p3 = q[3].x * zv.x + q[3].y * zv.y + q[3].z * zv.z + q[3].w * zv.w;

    // packed 4-head reduction over 16 lanes (xor 8 fold, xor 4 fold, xor 2/1)
    float send1 = bit3 ? p0 : p2;
    float recv1 = __shfl_xor(send1, 8);
    float a0 = (bit3 ? p2 : p0) + recv1;            // head bit3*2+0
    float send2 = bit3 ? p1h : p3;
    float recv2 = __shfl_xor(send2, 8);
    float a1 = (bit3 ? p3 : p1h) + recv2;           // head bit3*2+1
    float send3 = bit2 ? a0 : a1;
    float recv3 = __shfl_xor(send3, 4);
    float b = (bit2 ? a1 : a0) + recv3;             // head bit3*2+bit2
    b += __shfl_xor(b, 2);
    b += __shfl_xor(b, 1);

    // broadcast all 4 head sums back to every lane
    float r4 = __shfl_xor(b, 4);    // head e^1
    float r8 = __shfl_xor(b, 8);    // head e^2
    float r84 = __shfl_xor(r4, 8);  // head e^3
    float sc0 = bit3 ? (bit2 ? r84 : r8) : (bit2 ? r4 : b);
    float sc1 = bit3 ? (bit2 ? r8 : r84) : (bit2 ? b : r4);
    float sc2 = bit3 ? (bit2 ? r4 : b) : (bit2 ? r84 : r8);
    float sc3 = bit3 ? (bit2 ? b : r4) : (bit2 ? r8 : r84);

    float e0 = act ? __expf(fminf(sc0, 60.f)) : 0.f;
    float e1 = act ? __expf(fminf(sc1, 60.f)) : 0.f;
    float e2 = act ? __expf(fminf(sc2, 60.f)) : 0.f;
    float e3 = act ? __expf(fminf(sc3, 60.f)) : 0.f;

    den[0] += e0; den[1] += e1; den[2] += e2; den[3] += e3;
    ua[0].x += e0 * zv.x; ua[0].y += e0 * zv.y; ua[0].z += e0 * zv.z; ua[0].w += e0 * zv.w;
    ua[1].x += e1 * zv.x; ua[1].y += e1 * zv.y; ua[1].z += e1 * zv.z; ua[1].w += e1 * zv.w;
    ua[2].x += e2 * zv.x; ua[2].y += e2 * zv.y; ua[2].z += e2 * zv.z; ua[2].w += e2 * zv.w;
    ua[3].x += e3 * zv.x; ua[3].y += e3 * zv.y; ua[3].z += e3 * zv.z; ua[3].w += e3 * zv.w;
    ++p;
  }

  if (valid) {
#pragma unroll
    for (int h = 0; h < 4; ++h) {
      float inv = 1.0f / (den[h] + 1e-16f);
      float4 o;
      o.x = ua[h].x * inv; o.y = ua[h].y * inv;
      o.z = ua[h].z * inv; o.w = ua[h].w * inv;
      *reinterpret_cast<float4*>(u + (size_t)dst * 256 + h * 64 + t * 4) = o;
    }
  }
}

}  // namespace

extern "C" void kernel_launch(void* const* d_in, const int* in_sizes, int n_in,
                              void* d_out, int out_size, void* d_ws, size_t ws_size,
                              hipStream_t stream) {
  const float* x   = (const float*)d_in[0];
  const int*   ei  = (const int*)d_in[1];
  const float* ew  = (const float*)d_in[2];
  const float* W1  = (const float*)d_in[3];
  const float* b1  = (const float*)d_in[4];
  const float* g1  = (const float*)d_in[5];
  const float* be1 = (const float*)d_in[6];
  const float* m1  = (const float*)d_in[7];
  const float* v1  = (const float*)d_in[8];
  const float* W2  = (const float*)d_in[9];
  const float* b2  = (const float*)d_in[10];
  const float* g2  = (const float*)d_in[11];
  const float* be2 = (const float*)d_in[12];
  const float* m2  = (const float*)d_in[13];
  const float* v2  = (const float*)d_in[14];
  const float* Wq  = (const float*)d_in[15];
  const float* bq  = (const float*)d_in[16];
  const float* Wk  = (const float*)d_in[17];
  const float* Wv  = (const float*)d_in[19];
  const float* bv  = (const float*)d_in[20];
  const float* Wsk = (const float*)d_in[21];
  const float* bsk = (const float*)d_in[22];
  const float* gt  = (const float*)d_in[23];
  const float* bet = (const float*)d_in[24];
  const float* mt  = (const float*)d_in[25];
  const float* vt  = (const float*)d_in[26];
  const float* Wfc = (const float*)d_in[27];
  const float* bfc = (const float*)d_in[28];

  float* ws = (float*)d_ws;
  float* dinv    = ws;                          // N
  int*   cnt     = (int*)(dinv + NN);           // N
  int*   cur     = cnt + NN;                    // N
  int*   ro      = cur + NN;                    // N+1 (padded to 50016)
  int*   csr_src = ro + 50016;                  // E
  float* csr_nrm = (float*)(csr_src + EE);      // E
  int*   perm    = (int*)(csr_nrm + EE);        // N
  int*   bins    = perm + NN;                   // 64
  int*   bcur    = bins + 64;                   // 64
  float* h1      = (float*)(bcur + 64);         // N*128
  float* a1      = h1 + (size_t)NN * GH;        // N*128
  float* h2      = a1 + (size_t)NN * GH;        // N*64
  float* z       = h2 + (size_t)NN * GO;        // N*64
  float* qpp     = z + (size_t)NN * GO;         // N*256
  float* u       = qpp + (size_t)NN * 256;      // N*256
  float* agg     = u + (size_t)NN * 256;        // N*64
  float* Mc      = agg + (size_t)NN * GO;       // 64*256
  float* cvec    = Mc + 64 * 256;               // 256
  float* Bvm     = cvec + 256;                  // 256*64
  float* bvs     = Bvm + 256 * 64;              // 64
  unsigned short* W1p  = (unsigned short*)(bvs + 64);  // 2*512*128
  unsigned short* W2p  = W1p + 2 * 512 * 128;          // 2*128*64
  unsigned short* Mcp  = W2p + 2 * 128 * 64;           // 2*64*256
  unsigned short* Wskp = Mcp + 2 * 64 * 256;           // 2*64*64
  unsigned short* Bvp  = Wskp + 2 * 64 * 64;           // 2*256*64
  unsigned short* Wfcp = Bvp + 2 * 256 * 64;           // 2*64*32

  const int tb = 256;
  const int gM = cdiv(NN, 64);  // 782 row-blocks

  // graph prep + CSR + degree-sorted permutation
  k_init0<<<cdiv(NN, tb), tb, 0, stream>>>(dinv, cnt, cur, bins);
  k_edge1<<<cdiv(EE, tb), tb, 0, stream>>>(ei, ew, dinv, cnt);
  k_dinv<<<cdiv(NN, tb), tb, 0, stream>>>(dinv);
  k_scan<<<1, 1024, 0, stream>>>(cnt, ro);
  k_fill<<<cdiv(EE, tb), tb, 0, stream>>>(ei, ew, dinv, ro, cur, csr_src, csr_nrm);
  k_hist<<<cdiv(NN, tb), tb, 0, stream>>>(cnt, bins);
  k_binscan<<<1, 64, 0, stream>>>(bins, bcur);
  k_perm<<<cdiv(NN, tb), tb, 0, stream>>>(cnt, bcur, perm);

  // attention weight precompute + B splits
  k_prep_mc<<<64, 256, 0, stream>>>(Wq, Wk, bq, Mc, cvec);
  k_prep_bv<<<64, 256, 0, stream>>>(Wv, bv, Bvm, bvs);
  k_split<<<cdiv(512 * 128, tb), tb, 0, stream>>>(W1, W1p, 512, 128);
  k_split<<<cdiv(128 * 64, tb), tb, 0, stream>>>(W2, W2p, 128, 64);
  k_split<<<cdiv(64 * 256, tb), tb, 0, stream>>>(Mc, Mcp, 64, 256);
  k_split<<<cdiv(64 * 64, tb), tb, 0, stream>>>(Wsk, Wskp, 64, 64);
  k_split<<<cdiv(256 * 64, tb), tb, 0, stream>>>(Bvm, Bvp, 256, 64);
  k_split<<<cdiv(64 * 32, tb), tb, 0, stream>>>(Wfc, Wfcp, 64, 32);

  // GCN layer 1
  mgemm<128, false, false><<<dim3(gM, 1), 256, 0, stream>>>(
      x, W1p, nullptr, h1, NN, CIN, GH, nullptr, nullptr, nullptr, nullptr);
  k_gcn<GH><<<cdiv(NN, 4), 256, 0, stream>>>(ro, csr_src, csr_nrm, h1, dinv,
                                             b1, g1, be1, m1, v1, a1);
  // GCN layer 2
  mgemm<64, false, false><<<dim3(gM, 1), 256, 0, stream>>>(
      a1, W2p, nullptr, h2, NN, GH, GO, nullptr, nullptr, nullptr, nullptr);
  k_gcn<GO><<<cdiv(NN, 4), 256, 0, stream>>>(ro, csr_src, csr_nrm, h2, dinv,
                                             b2, g2, be2, m2, v2, z);

  // TransformerConv: Q'' = z @ Mc + cvec ; fused edge softmax
  mgemm<128, false, false><<<dim3(gM, 2), 256, 0, stream>>>(
      z, Mcp, cvec, qpp, NN, GO, 256, nullptr, nullptr, nullptr, nullptr);
  k_attn<<<cdiv(NN, 16), 256, 0, stream>>>(ro, csr_src, perm, z, qpp, u);

  // agg = z @ Wskip + bskip ; agg += u @ Bv + bvs ; BN_t + ReLU fused
  mgemm<64, false, false><<<dim3(gM, 1), 256, 0, stream>>>(
      z, Wskp, bsk, agg, NN, GO, GO, nullptr, nullptr, nullptr, nullptr);
  mgemm<64, true, true><<<dim3(gM, 1), 256, 0, stream>>>(
      u, Bvp, bvs, agg, NN, 256, GO, gt, bet, mt, vt);

  // final linear
  mgemm<32, false, false><<<dim3(gM, 1), 256, 0, stream>>>(
      agg, Wfcp, bfc, (float*)d_out, NN, GO, COUT, nullptr, nullptr, nullptr, nullptr);
}

// Round 5
// 381.530 us; speedup vs baseline: 1.8777x; 1.8777x over previous
//
#include <hip/hip_runtime.h>
#include <math.h>

namespace {

constexpr int NN = 50000;
constexpr int EE = 400000;
constexpr int CIN = 512;
constexpr int GH = 128;
constexpr int GO = 64;
constexpr int HEADS = 4;
constexpr int COUT = 32;
constexpr float EPS = 1e-5f;
constexpr int PBLK = (NN + 255) / 256;  // 196 blocks for per-block hist

typedef __attribute__((ext_vector_type(8))) short short8;
typedef __attribute__((ext_vector_type(4))) float f32x4;
typedef __attribute__((ext_vector_type(4))) unsigned int uint4v;

inline int cdiv(int a, int b) { return (a + b - 1) / b; }

__device__ __forceinline__ void split2(float x, unsigned short& hi, unsigned short& lo) {
  unsigned b = __float_as_uint(x);
  hi = (unsigned short)(b >> 16);
  float hf = __uint_as_float(b & 0xFFFF0000u);
  lo = (unsigned short)(__float_as_uint(x - hf) >> 16);
}

// ---- init ---------------------------------------------------------------
__global__ void k_init0(float* deg, int* cnt, int* cur) {
  int i = blockIdx.x * blockDim.x + threadIdx.x;
  if (i < NN) { deg[i] = 0.0f; cnt[i] = 0; cur[i] = 0; }
}

__global__ void k_edge1(const int* __restrict__ ei, const float* __restrict__ w,
                        float* __restrict__ deg, int* __restrict__ cnt) {
  int e = blockIdx.x * blockDim.x + threadIdx.x;
  if (e < EE) {
    int d = ei[EE + e];
    atomicAdd(&deg[d], w[e]);
    atomicAdd(&cnt[d], 1);
  }
}

__global__ void k_dinv(float* deg) {
  int i = blockIdx.x * blockDim.x + threadIdx.x;
  if (i < NN) deg[i] = rsqrtf(deg[i] + 1.0f);
}

// ---- contention-free counting sort by degree ----------------------------
// Pass A: per-block LDS histogram -> blkhist[block][64]
__global__ void k_bhist(const int* __restrict__ cnt, int* __restrict__ blkhist) {
  __shared__ int lh[64];
  const int tid = threadIdx.x;
  if (tid < 64) lh[tid] = 0;
  __syncthreads();
  int i = blockIdx.x * 256 + tid;
  if (i < NN) atomicAdd(&lh[min(cnt[i], 63)], 1);
  __syncthreads();
  if (tid < 64) blkhist[blockIdx.x * 64 + tid] = lh[tid];
}

// Pass B: one 64-thread block: blkoff[block][bin] = binbase[bin] + cumsum
__global__ void k_boff(const int* __restrict__ blkhist, int* __restrict__ blkoff) {
  const int b = threadIdx.x;  // bin 0..63
  int tot = 0;
  for (int k = 0; k < PBLK; ++k) tot += blkhist[k * 64 + b];
  int x = tot;
#pragma unroll
  for (int s = 1; s < 64; s <<= 1) {
    int t = __shfl_up(x, s);
    if (b >= s) x += t;
  }
  int run = x - tot;  // exclusive bin base
  for (int k = 0; k < PBLK; ++k) {
    int c = blkhist[k * 64 + b];
    blkoff[k * 64 + b] = run;
    run += c;
  }
}

// Pass C: per-block LDS-atomic local rank, write perm
__global__ void k_perm2(const int* __restrict__ cnt, const int* __restrict__ blkoff,
                        int* __restrict__ perm) {
  __shared__ int lcur[64];
  const int tid = threadIdx.x;
  if (tid < 64) lcur[tid] = 0;
  __syncthreads();
  int i = blockIdx.x * 256 + tid;
  if (i < NN) {
    int b = min(cnt[i], 63);
    int r = atomicAdd(&lcur[b], 1);
    perm[blkoff[blockIdx.x * 64 + b] + r] = i;
  }
}

// ---- exclusive scan of cnt[NN] -> ro, single block ----------------------
__launch_bounds__(1024) __global__ void k_scan(const int* __restrict__ cnt,
                                               int* __restrict__ ro) {
  __shared__ int wsum[16];
  __shared__ int carry_s;
  const int tid = threadIdx.x;
  const int lane = tid & 63;
  const int wv = tid >> 6;
  if (tid == 0) carry_s = 0;
  __syncthreads();
  for (int base = 0; base < NN; base += 1024) {
    int idx = base + tid;
    int v = idx < NN ? cnt[idx] : 0;
    int x = v;
#pragma unroll
    for (int s = 1; s < 64; s <<= 1) {
      int t = __shfl_up(x, s);
      if (lane >= s) x += t;
    }
    if (lane == 63) wsum[wv] = x;
    __syncthreads();
    if (wv == 0 && lane < 16) {
      int wsc = wsum[lane];
#pragma unroll
      for (int s = 1; s < 16; s <<= 1) {
        int t = __shfl_up(wsc, s);
        if (lane >= s) wsc += t;
      }
      wsum[lane] = wsc;
    }
    __syncthreads();
    int waveoff = (wv == 0) ? 0 : wsum[wv - 1];
    int carry = carry_s;
    if (idx < NN) ro[idx] = carry + waveoff + x - v;
    __syncthreads();
    if (tid == 1023) carry_s = carry + wsum[15];
    __syncthreads();
  }
  if (threadIdx.x == 0) ro[NN] = carry_s;
}

__global__ void k_fill(const int* __restrict__ ei, const float* __restrict__ w,
                       const float* __restrict__ dinv, const int* __restrict__ ro,
                       int* __restrict__ cur, int* __restrict__ csr_src,
                       float* __restrict__ csr_nrm) {
  int e = blockIdx.x * blockDim.x + threadIdx.x;
  if (e >= EE) return;
  int s = ei[e], d = ei[EE + e];
  int p = ro[d] + atomicAdd(&cur[d], 1);
  csr_src[p] = s;
  csr_nrm[p] = dinv[s] * w[e] * dinv[d];
}

// ---- B-matrix hi/lo split + transpose -----------------------------------
__global__ void k_split(const float* __restrict__ B, unsigned short* __restrict__ Bp,
                        int K, int F) {
  int idx = blockIdx.x * blockDim.x + threadIdx.x;
  if (idx >= K * F) return;
  int k = idx / F, f = idx - k * F;
  unsigned short hi, lo;
  split2(B[idx], hi, lo);
  Bp[f * K + k] = hi;
  Bp[(size_t)F * K + f * K + k] = lo;
}

// ---- MFMA GEMM ----------------------------------------------------------
template <int BN, bool ACC, bool BNR>
__launch_bounds__(256, 2) __global__
void mgemm(const float* __restrict__ A, const unsigned short* __restrict__ Bp,
           const float* __restrict__ bias, float* __restrict__ C,
           int M, int K, int F,
           const float* __restrict__ bn_g, const float* __restrict__ bn_b,
           const float* __restrict__ bn_m, const float* __restrict__ bn_v) {
  constexpr int BM = 64;
  constexpr int BK = 64;
  constexpr int NR = BN / 32;

  __shared__ unsigned short lds[(BM + BN) * BK * 2];
  unsigned short* Ah = lds;
  unsigned short* Al = Ah + BM * BK;
  unsigned short* Bh = Al + BM * BK;
  unsigned short* Bl = Bh + BN * BK;

  const int tid = threadIdx.x;
  const int lane = tid & 63;
  const int wid = tid >> 6;
  const int wr = wid >> 1, wc = wid & 1;
  const int l15 = lane & 15, lhi = lane >> 4;
  const int m0 = blockIdx.x * BM;
  const int n0 = blockIdx.y * BN;

  f32x4 acc[2][NR];
#pragma unroll
  for (int mi = 0; mi < 2; ++mi)
#pragma unroll
    for (int ni = 0; ni < NR; ++ni) acc[mi][ni] = (f32x4)0.0f;

  for (int k0 = 0; k0 < K; k0 += BK) {
    {
      const int r = tid >> 2, ch = tid & 3;
      const int gr = m0 + r;
      float xv[16];
      if (gr < M) {
        const float4* src =
            reinterpret_cast<const float4*>(A + (size_t)gr * K + k0 + ch * 16);
#pragma unroll
        for (int i = 0; i < 4; ++i) {
          float4 f = src[i];
          xv[i * 4 + 0] = f.x; xv[i * 4 + 1] = f.y;
          xv[i * 4 + 2] = f.z; xv[i * 4 + 3] = f.w;
        }
      } else {
#pragma unroll
        for (int i = 0; i < 16; ++i) xv[i] = 0.0f;
      }
      short8 vh0, vl0, vh1, vl1;
#pragma unroll
      for (int i = 0; i < 8; ++i) {
        unsigned short h, l;
        split2(xv[i], h, l);
        vh0[i] = (short)h; vl0[i] = (short)l;
      }
#pragma unroll
      for (int i = 0; i < 8; ++i) {
        unsigned short h, l;
        split2(xv[8 + i], h, l);
        vh1[i] = (short)h; vl1[i] = (short)l;
      }
      const int base = r * 128 + ch * 32;
      const int sw = (r & 7) << 4;
      *reinterpret_cast<short8*>((char*)Ah + (base ^ sw)) = vh0;
      *reinterpret_cast<short8*>((char*)Ah + ((base + 16) ^ sw)) = vh1;
      *reinterpret_cast<short8*>((char*)Al + (base ^ sw)) = vl0;
      *reinterpret_cast<short8*>((char*)Al + ((base + 16) ^ sw)) = vl1;
    }
    {
#pragma unroll
      for (int it = 0; it < BN / 16; ++it) {
        int id = tid + it * 256;
        int kc = id & 7;
        int colp = id >> 3;
        int col = colp & (BN - 1);
        int plane = colp >> (BN == 32 ? 5 : (BN == 64 ? 6 : 7));
        const uint4v gv = *reinterpret_cast<const uint4v*>(
            Bp + ((size_t)plane * F + n0 + col) * K + k0 + kc * 8);
        unsigned short* dst = plane ? Bl : Bh;
        const int base = col * 128 + kc * 16;
        *reinterpret_cast<uint4v*>((char*)dst + (base ^ ((col & 7) << 4))) = gv;
      }
    }
    __syncthreads();

#pragma unroll
    for (int ks = 0; ks < 2; ++ks) {
      short8 ahf[2], alf[2], bhf[NR], blf[NR];
#pragma unroll
      for (int mi = 0; mi < 2; ++mi) {
        int row = wr * 32 + mi * 16 + l15;
        int off = (row * 128 + (ks * 32 + lhi * 8) * 2) ^ ((row & 7) << 4);
        ahf[mi] = *reinterpret_cast<const short8*>((const char*)Ah + off);
        alf[mi] = *reinterpret_cast<const short8*>((const char*)Al + off);
      }
#pragma unroll
      for (int ni = 0; ni < NR; ++ni) {
        int col = wc * (BN / 2) + ni * 16 + l15;
        int off = (col * 128 + (ks * 32 + lhi * 8) * 2) ^ ((col & 7) << 4);
        bhf[ni] = *reinterpret_cast<const short8*>((const char*)Bh + off);
        blf[ni] = *reinterpret_cast<const short8*>((const char*)Bl + off);
      }
#pragma unroll
      for (int mi = 0; mi < 2; ++mi)
#pragma unroll
        for (int ni = 0; ni < NR; ++ni) {
          acc[mi][ni] = __builtin_amdgcn_mfma_f32_16x16x32_bf16(
              ahf[mi], bhf[ni], acc[mi][ni], 0, 0, 0);
          acc[mi][ni] = __builtin_amdgcn_mfma_f32_16x16x32_bf16(
              ahf[mi], blf[ni], acc[mi][ni], 0, 0, 0);
          acc[mi][ni] = __builtin_amdgcn_mfma_f32_16x16x32_bf16(
              alf[mi], bhf[ni], acc[mi][ni], 0, 0, 0);
        }
    }
    __syncthreads();
  }

#pragma unroll
  for (int mi = 0; mi < 2; ++mi) {
#pragma unroll
    for (int ni = 0; ni < NR; ++ni) {
      const int col = n0 + wc * (BN / 2) + ni * 16 + l15;
      const float bv = bias ? bias[col] : 0.0f;
      float bns = 0.f, bnb = 0.f, bnm = 0.f;
      if (BNR) {
        bns = bn_g[col] * rsqrtf(bn_v[col] + EPS);
        bnb = bn_b[col];
        bnm = bn_m[col];
      }
#pragma unroll
      for (int r4 = 0; r4 < 4; ++r4) {
        const int row = m0 + wr * 32 + mi * 16 + lhi * 4 + r4;
        if (row < M) {
          float vout = acc[mi][ni][r4] + bv;
          if (ACC) vout += C[(size_t)row * F + col];
          if (BNR) {
            vout = (vout - bnm) * bns + bnb;
            vout = vout > 0.f ? vout : 0.f;
          }
          C[(size_t)row * F + col] = vout;
        }
      }
    }
  }
}

// ---- GCN propagate (CSR gather) + BN + ReLU, wave per dst, unroll 4 -----
template <int F>
__launch_bounds__(256) __global__
void k_gcn(const int* __restrict__ ro, const int* __restrict__ csr_src,
           const float* __restrict__ csr_nrm, const float* __restrict__ h,
           const float* __restrict__ dinv, const float* __restrict__ bias,
           const float* __restrict__ g, const float* __restrict__ be,
           const float* __restrict__ m, const float* __restrict__ v,
           float* __restrict__ out) {
  const int wid = blockIdx.x * 4 + (threadIdx.x >> 6);
  const int lane = threadIdx.x & 63;
  if (wid >= NN) return;
  const float di = dinv[wid];
  const float di2 = di * di;
  const int p0 = ro[wid], p1 = ro[wid + 1];

  if (F == 128) {
    float2 a0 = reinterpret_cast<const float2*>(h + (size_t)wid * 128)[lane];
    a0.x *= di2; a0.y *= di2;
    float2 a1 = make_float2(0.f, 0.f), a2 = make_float2(0.f, 0.f),
           a3 = make_float2(0.f, 0.f);
    int p = p0;
    for (; p + 4 <= p1; p += 4) {
      int s0 = csr_src[p], s1 = csr_src[p + 1], s2 = csr_src[p + 2],
          s3 = csr_src[p + 3];
      float w0 = csr_nrm[p], w1 = csr_nrm[p + 1], w2 = csr_nrm[p + 2],
            w3 = csr_nrm[p + 3];
      float2 h0 = reinterpret_cast<const float2*>(h + (size_t)s0 * 128)[lane];
      float2 h1 = reinterpret_cast<const float2*>(h + (size_t)s1 * 128)[lane];
      float2 h2 = reinterpret_cast<const float2*>(h + (size_t)s2 * 128)[lane];
      float2 h3 = reinterpret_cast<const float2*>(h + (size_t)s3 * 128)[lane];
      a0.x += w0 * h0.x; a0.y += w0 * h0.y;
      a1.x += w1 * h1.x; a1.y += w1 * h1.y;
      a2.x += w2 * h2.x; a2.y += w2 * h2.y;
      a3.x += w3 * h3.x; a3.y += w3 * h3.y;
    }
    for (; p < p1; ++p) {
      int s = csr_src[p];
      float w = csr_nrm[p];
      float2 hv = reinterpret_cast<const float2*>(h + (size_t)s * 128)[lane];
      a1.x += w * hv.x; a1.y += w * hv.y;
    }
    float2 a;
    a.x = (a0.x + a1.x) + (a2.x + a3.x);
    a.y = (a0.y + a1.y) + (a2.y + a3.y);
    float2 gg = reinterpret_cast<const float2*>(g)[lane];
    float2 bb = reinterpret_cast<const float2*>(be)[lane];
    float2 mm = reinterpret_cast<const float2*>(m)[lane];
    float2 vv = reinterpret_cast<const float2*>(v)[lane];
    float2 bi = bias ? reinterpret_cast<const float2*>(bias)[lane]
                     : make_float2(0.f, 0.f);
    float s0 = gg.x * rsqrtf(vv.x + EPS);
    float s1 = gg.y * rsqrtf(vv.y + EPS);
    float y0 = (a.x + bi.x - mm.x) * s0 + bb.x;
    float y1 = (a.y + bi.y - mm.y) * s1 + bb.y;
    float2 o;
    o.x = y0 > 0.f ? y0 : 0.f;
    o.y = y1 > 0.f ? y1 : 0.f;
    reinterpret_cast<float2*>(out + (size_t)wid * 128)[lane] = o;
  } else {
    float a0 = h[(size_t)wid * F + lane] * di2;
    float a1 = 0.f, a2 = 0.f, a3 = 0.f;
    int p = p0;
    for (; p + 4 <= p1; p += 4) {
      int s0 = csr_src[p], s1 = csr_src[p + 1], s2 = csr_src[p + 2],
          s3 = csr_src[p + 3];
      float w0 = csr_nrm[p], w1 = csr_nrm[p + 1], w2 = csr_nrm[p + 2],
            w3 = csr_nrm[p + 3];
      a0 += w0 * h[(size_t)s0 * F + lane];
      a1 += w1 * h[(size_t)s1 * F + lane];
      a2 += w2 * h[(size_t)s2 * F + lane];
      a3 += w3 * h[(size_t)s3 * F + lane];
    }
    for (; p < p1; ++p) a1 += csr_nrm[p] * h[(size_t)csr_src[p] * F + lane];
    float a = (a0 + a1) + (a2 + a3);
    float sc = g[lane] * rsqrtf(v[lane] + EPS);
    float bi = bias ? bias[lane] : 0.f;
    float y = (a + bi - m[lane]) * sc + be[lane];
    out[(size_t)wid * F + lane] = y > 0.f ? y : 0.f;
  }
}

// ---- attention precompute: Mc[64][256], cvec[256] -----------------------
__global__ void k_prep_mc(const float* __restrict__ Wq, const float* __restrict__ Wk,
                          const float* __restrict__ bq, float* __restrict__ Mc,
                          float* __restrict__ cvec) {
  int i = blockIdx.x;
  int col = threadIdx.x;
  int h = col >> 6, j = col & 63;
  float acc = 0.f;
  for (int t = 0; t < 64; ++t)
    acc += Wq[i * 256 + h * 64 + t] * Wk[j * 256 + h * 64 + t];
  Mc[i * 256 + col] = 0.125f * acc;
  if (i == 0) {
    float c = 0.f;
    for (int t = 0; t < 64; ++t) c += bq[h * 64 + t] * Wk[j * 256 + h * 64 + t];
    cvec[col] = 0.125f * c;
  }
}

__global__ void k_prep_bv(const float* __restrict__ Wv, const float* __restrict__ bv,
                          float* __restrict__ Bv, float* __restrict__ bvs) {
  int idx = blockIdx.x * blockDim.x + threadIdx.x;
  if (idx < 256 * 64) {
    int r = idx >> 6, t = idx & 63;
    int h = r >> 6, c = r & 63;
    Bv[idx] = 0.25f * Wv[c * 256 + h * 64 + t];
  }
  if (blockIdx.x == 0 && threadIdx.x < 64) {
    int t = threadIdx.x;
    float s = 0.f;
    for (int h = 0; h < HEADS; ++h) s += bv[h * 64 + t];
    bvs[t] = 0.25f * s;
  }
}

// ---- fused edge-softmax attention: 16 lanes per dst, 4 dsts per wave ----
__launch_bounds__(256) __global__
void k_attn(const int* __restrict__ ro, const int* __restrict__ csr_src,
            const int* __restrict__ perm, const float* __restrict__ z,
            const float* __restrict__ qpp, float* __restrict__ u) {
  const int wave = blockIdx.x * 4 + (threadIdx.x >> 6);
  const int lane = threadIdx.x & 63;
  const int g = lane >> 4;   // dst group 0..3
  const int t = lane & 15;   // sublane
  const bool bit3 = (t & 8) != 0, bit2 = (t & 4) != 0;

  const int idx = wave * 4 + g;
  const bool valid = idx < NN;
  const int dst = perm[valid ? idx : 0];

  float4 q[4];
#pragma unroll
  for (int h = 0; h < 4; ++h)
    q[h] = *reinterpret_cast<const float4*>(qpp + (size_t)dst * 256 + h * 64 + t * 4);

  float4 ua[4];
  float den[4];
#pragma unroll
  for (int h = 0; h < 4; ++h) {
    ua[h] = make_float4(0.f, 0.f, 0.f, 0.f);
    den[h] = 0.f;
  }

  int p = valid ? ro[dst] : 0;
  int p1 = valid ? ro[dst + 1] : 0;

  while (__ballot(p < p1)) {
    const bool act = p < p1;
    const int pc = act ? p : 0;
    const int s = csr_src[pc];
    const float4 zv = *reinterpret_cast<const float4*>(z + (size_t)s * 64 + t * 4);

    float p0 = q[0].x * zv.x + q[0].y * zv.y + q[0].z * zv.z + q[0].w * zv.w;
    float p1h = q[1].x * zv.x + q[1].y * zv.y + q[1].z * zv.z + q[1].w * zv.w;
    float p2 = q[2].x * zv.x + q[2].y * zv.y + q[2].z * zv.z + q[2].w * zv.w;
    float p3 = q[3].x * zv.x + q[3].y * zv.y + q[3].z * zv.z + q[3].w * zv.w;

    float send1 = bit3 ? p0 : p2;
    float recv1 = __shfl_xor(send1, 8);
    float a0 = (bit3 ? p2 : p0) + recv1;
    float send2 = bit3 ? p1h : p3;
    float recv2 = __shfl_xor(send2, 8);
    float a1 = (bit3 ? p3 : p1h) + recv2;
    float send3 = bit2 ? a0 : a1;
    float recv3 = __shfl_xor(send3, 4);
    float b = (bit2 ? a1 : a0) + recv3;
    b += __shfl_xor(b, 2);
    b += __shfl_xor(b, 1);

    float r4 = __shfl_xor(b, 4);
    float r8 = __shfl_xor(b, 8);
    float r84 = __shfl_xor(r4, 8);
    float sc0 = bit3 ? (bit2 ? r84 : r8) : (bit2 ? r4 : b);
    float sc1 = bit3 ? (bit2 ? r8 : r84) : (bit2 ? b : r4);
    float sc2 = bit3 ? (bit2 ? r4 : b) : (bit2 ? r84 : r8);
    float sc3 = bit3 ? (bit2 ? b : r4) : (bit2 ? r8 : r84);

    float e0 = act ? __expf(fminf(sc0, 60.f)) : 0.f;
    float e1 = act ? __expf(fminf(sc1, 60.f)) : 0.f;
    float e2 = act ? __expf(fminf(sc2, 60.f)) : 0.f;
    float e3 = act ? __expf(fminf(sc3, 60.f)) : 0.f;

    den[0] += e0; den[1] += e1; den[2] += e2; den[3] += e3;
    ua[0].x += e0 * zv.x; ua[0].y += e0 * zv.y; ua[0].z += e0 * zv.z; ua[0].w += e0 * zv.w;
    ua[1].x += e1 * zv.x; ua[1].y += e1 * zv.y; ua[1].z += e1 * zv.z; ua[1].w += e1 * zv.w;
    ua[2].x += e2 * zv.x; ua[2].y += e2 * zv.y; ua[2].z += e2 * zv.z; ua[2].w += e2 * zv.w;
    ua[3].x += e3 * zv.x; ua[3].y += e3 * zv.y; ua[3].z += e3 * zv.z; ua[3].w += e3 * zv.w;
    ++p;
  }

  if (valid) {
#pragma unroll
    for (int h = 0; h < 4; ++h) {
      float inv = 1.0f / (den[h] + 1e-16f);
      float4 o;
      o.x = ua[h].x * inv; o.y = ua[h].y * inv;
      o.z = ua[h].z * inv; o.w = ua[h].w * inv;
      *reinterpret_cast<float4*>(u + (size_t)dst * 256 + h * 64 + t * 4) = o;
    }
  }
}

}  // namespace

extern "C" void kernel_launch(void* const* d_in, const int* in_sizes, int n_in,
                              void* d_out, int out_size, void* d_ws, size_t ws_size,
                              hipStream_t stream) {
  const float* x   = (const float*)d_in[0];
  const int*   ei  = (const int*)d_in[1];
  const float* ew  = (const float*)d_in[2];
  const float* W1  = (const float*)d_in[3];
  const float* b1  = (const float*)d_in[4];
  const float* g1  = (const float*)d_in[5];
  const float* be1 = (const float*)d_in[6];
  const float* m1  = (const float*)d_in[7];
  const float* v1  = (const float*)d_in[8];
  const float* W2  = (const float*)d_in[9];
  const float* b2  = (const float*)d_in[10];
  const float* g2  = (const float*)d_in[11];
  const float* be2 = (const float*)d_in[12];
  const float* m2  = (const float*)d_in[13];
  const float* v2  = (const float*)d_in[14];
  const float* Wq  = (const float*)d_in[15];
  const float* bq  = (const float*)d_in[16];
  const float* Wk  = (const float*)d_in[17];
  const float* Wv  = (const float*)d_in[19];
  const float* bv  = (const float*)d_in[20];
  const float* Wsk = (const float*)d_in[21];
  const float* bsk = (const float*)d_in[22];
  const float* gt  = (const float*)d_in[23];
  const float* bet = (const float*)d_in[24];
  const float* mt  = (const float*)d_in[25];
  const float* vt  = (const float*)d_in[26];
  const float* Wfc = (const float*)d_in[27];
  const float* bfc = (const float*)d_in[28];

  float* ws = (float*)d_ws;
  float* dinv    = ws;                          // N
  int*   cnt     = (int*)(dinv + NN);           // N
  int*   cur     = cnt + NN;                    // N
  int*   ro      = cur + NN;                    // N+1 (padded to 50016)
  int*   csr_src = ro + 50016;                  // E
  float* csr_nrm = (float*)(csr_src + EE);      // E
  int*   perm    = (int*)(csr_nrm + EE);        // N
  int*   blkhist = perm + NN;                   // PBLK*64
  int*   blkoff  = blkhist + PBLK * 64;         // PBLK*64
  float* h1      = (float*)(blkoff + PBLK * 64);  // N*128
  float* a1      = h1 + (size_t)NN * GH;        // N*128
  float* h2      = a1 + (size_t)NN * GH;        // N*64
  float* z       = h2 + (size_t)NN * GO;        // N*64
  float* qpp     = z + (size_t)NN * GO;         // N*256
  float* u       = qpp + (size_t)NN * 256;      // N*256
  float* agg     = u + (size_t)NN * 256;        // N*64
  float* Mc      = agg + (size_t)NN * GO;       // 64*256
  float* cvec    = Mc + 64 * 256;               // 256
  float* Bvm     = cvec + 256;                  // 256*64
  float* bvs     = Bvm + 256 * 64;              // 64
  unsigned short* W1p  = (unsigned short*)(bvs + 64);  // 2*512*128
  unsigned short* W2p  = W1p + 2 * 512 * 128;          // 2*128*64
  unsigned short* Mcp  = W2p + 2 * 128 * 64;           // 2*64*256
  unsigned short* Wskp = Mcp + 2 * 64 * 256;           // 2*64*64
  unsigned short* Bvp  = Wskp + 2 * 64 * 64;           // 2*256*64
  unsigned short* Wfcp = Bvp + 2 * 256 * 64;           // 2*64*32

  const int tb = 256;
  const int gM = cdiv(NN, 64);  // 782 row-blocks

  // graph prep + CSR + contention-free degree sort
  k_init0<<<cdiv(NN, tb), tb, 0, stream>>>(dinv, cnt, cur);
  k_edge1<<<cdiv(EE, tb), tb, 0, stream>>>(ei, ew, dinv, cnt);
  k_dinv<<<cdiv(NN, tb), tb, 0, stream>>>(dinv);
  k_scan<<<1, 1024, 0, stream>>>(cnt, ro);
  k_fill<<<cdiv(EE, tb), tb, 0, stream>>>(ei, ew, dinv, ro, cur, csr_src, csr_nrm);
  k_bhist<<<PBLK, 256, 0, stream>>>(cnt, blkhist);
  k_boff<<<1, 64, 0, stream>>>(blkhist, blkoff);
  k_perm2<<<PBLK, 256, 0, stream>>>(cnt, blkoff, perm);

  // attention weight precompute + B splits
  k_prep_mc<<<64, 256, 0, stream>>>(Wq, Wk, bq, Mc, cvec);
  k_prep_bv<<<64, 256, 0, stream>>>(Wv, bv, Bvm, bvs);
  k_split<<<cdiv(512 * 128, tb), tb, 0, stream>>>(W1, W1p, 512, 128);
  k_split<<<cdiv(128 * 64, tb), tb, 0, stream>>>(W2, W2p, 128, 64);
  k_split<<<cdiv(64 * 256, tb), tb, 0, stream>>>(Mc, Mcp, 64, 256);
  k_split<<<cdiv(64 * 64, tb), tb, 0, stream>>>(Wsk, Wskp, 64, 64);
  k_split<<<cdiv(256 * 64, tb), tb, 0, stream>>>(Bvm, Bvp, 256, 64);
  k_split<<<cdiv(64 * 32, tb), tb, 0, stream>>>(Wfc, Wfcp, 64, 32);

  // GCN layer 1
  mgemm<128, false, false><<<dim3(gM, 1), 256, 0, stream>>>(
      x, W1p, nullptr, h1, NN, CIN, GH, nullptr, nullptr, nullptr, nullptr);
  k_gcn<GH><<<cdiv(NN, 4), 256, 0, stream>>>(ro, csr_src, csr_nrm, h1, dinv,
                                             b1, g1, be1, m1, v1, a1);
  // GCN layer 2
  mgemm<64, false, false><<<dim3(gM, 1), 256, 0, stream>>>(
      a1, W2p, nullptr, h2, NN, GH, GO, nullptr, nullptr, nullptr, nullptr);
  k_gcn<GO><<<cdiv(NN, 4), 256, 0, stream>>>(ro, csr_src, csr_nrm, h2, dinv,
                                             b2, g2, be2, m2, v2, z);

  // TransformerConv: Q'' = z @ Mc + cvec ; fused edge softmax
  mgemm<128, false, false><<<dim3(gM, 2), 256, 0, stream>>>(
      z, Mcp, cvec, qpp, NN, GO, 256, nullptr, nullptr, nullptr, nullptr);
  k_attn<<<cdiv(NN, 16), 256, 0, stream>>>(ro, csr_src, perm, z, qpp, u);

  // agg = z @ Wskip + bskip ; agg += u @ Bv + bvs ; BN_t + ReLU fused
  mgemm<64, false, false><<<dim3(gM, 1), 256, 0, stream>>>(
      z, Wskp, bsk, agg, NN, GO, GO, nullptr, nullptr, nullptr, nullptr);
  mgemm<64, true, true><<<dim3(gM, 1), 256, 0, stream>>>(
      u, Bvp, bvs, agg, NN, 256, GO, gt, bet, mt, vt);

  // final linear
  mgemm<32, false, false><<<dim3(gM, 1), 256, 0, stream>>>(
      agg, Wfcp, bfc, (float*)d_out, NN, GO, COUT, nullptr, nullptr, nullptr, nullptr);
}

// Round 6
// 348.125 us; speedup vs baseline: 2.0579x; 1.0960x over previous
//
#include <hip/hip_runtime.h>
#include <math.h>

namespace {

constexpr int NN = 50000;
constexpr int EE = 400000;
constexpr int CIN = 512;
constexpr int GH = 128;
constexpr int GO = 64;
constexpr int HEADS = 4;
constexpr int COUT = 32;
constexpr float EPS = 1e-5f;
constexpr int PBLK = (NN + 255) / 256;  // 196

typedef __attribute__((ext_vector_type(8))) _Float16 half8;
typedef __attribute__((ext_vector_type(4))) float f32x4;
typedef __attribute__((ext_vector_type(4))) unsigned int uint4v;

inline int cdiv(int a, int b) { return (a + b - 1) / b; }

// ---- init ---------------------------------------------------------------
__global__ void k_init0(float* deg, int* cnt, int* cur) {
  int i = blockIdx.x * blockDim.x + threadIdx.x;
  if (i < NN) { deg[i] = 0.0f; cnt[i] = 0; cur[i] = 0; }
}

__global__ void k_edge1(const int* __restrict__ ei, const float* __restrict__ w,
                        float* __restrict__ deg, int* __restrict__ cnt) {
  int e = blockIdx.x * blockDim.x + threadIdx.x;
  if (e < EE) {
    int d = ei[EE + e];
    atomicAdd(&deg[d], w[e]);
    atomicAdd(&cnt[d], 1);
  }
}

__global__ void k_dinv(float* deg) {
  int i = blockIdx.x * blockDim.x + threadIdx.x;
  if (i < NN) deg[i] = rsqrtf(deg[i] + 1.0f);
}

// ---- contention-free counting sort by degree ----------------------------
__global__ void k_bhist(const int* __restrict__ cnt, int* __restrict__ blkhist) {
  __shared__ int lh[64];
  const int tid = threadIdx.x;
  if (tid < 64) lh[tid] = 0;
  __syncthreads();
  int i = blockIdx.x * 256 + tid;
  if (i < NN) atomicAdd(&lh[min(cnt[i], 63)], 1);
  __syncthreads();
  if (tid < 64) blkhist[blockIdx.x * 64 + tid] = lh[tid];
}

__global__ void k_boff(const int* __restrict__ blkhist, int* __restrict__ blkoff) {
  const int b = threadIdx.x;
  int tot = 0;
  for (int k = 0; k < PBLK; ++k) tot += blkhist[k * 64 + b];
  int x = tot;
#pragma unroll
  for (int s = 1; s < 64; s <<= 1) {
    int t = __shfl_up(x, s);
    if (b >= s) x += t;
  }
  int run = x - tot;
  for (int k = 0; k < PBLK; ++k) {
    int c = blkhist[k * 64 + b];
    blkoff[k * 64 + b] = run;
    run += c;
  }
}

__global__ void k_perm2(const int* __restrict__ cnt, const int* __restrict__ blkoff,
                        int* __restrict__ perm) {
  __shared__ int lcur[64];
  const int tid = threadIdx.x;
  if (tid < 64) lcur[tid] = 0;
  __syncthreads();
  int i = blockIdx.x * 256 + tid;
  if (i < NN) {
    int b = min(cnt[i], 63);
    int r = atomicAdd(&lcur[b], 1);
    perm[blkoff[blockIdx.x * 64 + b] + r] = i;
  }
}

// ---- exclusive scan of cnt[NN] -> ro, single block ----------------------
__launch_bounds__(1024) __global__ void k_scan(const int* __restrict__ cnt,
                                               int* __restrict__ ro) {
  __shared__ int wsum[16];
  __shared__ int carry_s;
  const int tid = threadIdx.x;
  const int lane = tid & 63;
  const int wv = tid >> 6;
  if (tid == 0) carry_s = 0;
  __syncthreads();
  for (int base = 0; base < NN; base += 1024) {
    int idx = base + tid;
    int v = idx < NN ? cnt[idx] : 0;
    int x = v;
#pragma unroll
    for (int s = 1; s < 64; s <<= 1) {
      int t = __shfl_up(x, s);
      if (lane >= s) x += t;
    }
    if (lane == 63) wsum[wv] = x;
    __syncthreads();
    if (wv == 0 && lane < 16) {
      int wsc = wsum[lane];
#pragma unroll
      for (int s = 1; s < 16; s <<= 1) {
        int t = __shfl_up(wsc, s);
        if (lane >= s) wsc += t;
      }
      wsum[lane] = wsc;
    }
    __syncthreads();
    int waveoff = (wv == 0) ? 0 : wsum[wv - 1];
    int carry = carry_s;
    if (idx < NN) ro[idx] = carry + waveoff + x - v;
    __syncthreads();
    if (tid == 1023) carry_s = carry + wsum[15];
    __syncthreads();
  }
  if (threadIdx.x == 0) ro[NN] = carry_s;
}

__global__ void k_fill(const int* __restrict__ ei, const float* __restrict__ w,
                       const float* __restrict__ dinv, const int* __restrict__ ro,
                       int* __restrict__ cur, int* __restrict__ csr_src,
                       float* __restrict__ csr_nrm) {
  int e = blockIdx.x * blockDim.x + threadIdx.x;
  if (e >= EE) return;
  int s = ei[e], d = ei[EE + e];
  int p = ro[d] + atomicAdd(&cur[d], 1);
  csr_src[p] = s;
  csr_nrm[p] = dinv[s] * w[e] * dinv[d];
}

// ---- attention precompute: Mc[64][256], cvec[256] -----------------------
__global__ void k_prep_mc(const float* __restrict__ Wq, const float* __restrict__ Wk,
                          const float* __restrict__ bq, float* __restrict__ Mc,
                          float* __restrict__ cvec) {
  int i = blockIdx.x;
  int col = threadIdx.x;
  int h = col >> 6, j = col & 63;
  float acc = 0.f;
  for (int t = 0; t < 64; ++t)
    acc += Wq[i * 256 + h * 64 + t] * Wk[j * 256 + h * 64 + t];
  Mc[i * 256 + col] = 0.125f * acc;
  if (i == 0) {
    float c = 0.f;
    for (int t = 0; t < 64; ++t) c += bq[h * 64 + t] * Wk[j * 256 + h * 64 + t];
    cvec[col] = 0.125f * c;
  }
}

// Bvm[256][64] = 0.25*Wv permuted ; bcomb[64] = bsk + 0.25*sum_h bv
__global__ void k_prep_bv(const float* __restrict__ Wv, const float* __restrict__ bv,
                          const float* __restrict__ bsk, float* __restrict__ Bvm,
                          float* __restrict__ bcomb) {
  int idx = blockIdx.x * blockDim.x + threadIdx.x;
  if (idx < 256 * 64) {
    int r = idx >> 6, t = idx & 63;
    int h = r >> 6, c = r & 63;
    Bvm[idx] = 0.25f * Wv[c * 256 + h * 64 + t];
  }
  if (blockIdx.x == 0 && threadIdx.x < 64) {
    int t = threadIdx.x;
    float s = 0.f;
    for (int h = 0; h < HEADS; ++h) s += bv[h * 64 + t];
    bcomb[t] = bsk[t] + 0.25f * s;
  }
}

// ---- merged weight convert+transpose to f16: dst[f*Ktot + koff + k] -----
__global__ void k_cvt(const float* __restrict__ W1, const float* __restrict__ W2,
                      const float* __restrict__ Mc, const float* __restrict__ Wsk,
                      const float* __restrict__ Bvm, const float* __restrict__ Wfc,
                      _Float16* __restrict__ W1p, _Float16* __restrict__ W2p,
                      _Float16* __restrict__ Mcp, _Float16* __restrict__ Bcatp,
                      _Float16* __restrict__ Wfcp) {
  int i = blockIdx.x * 256 + threadIdx.x;
  const float* src;
  _Float16* dst;
  int F, Ktot, koff, rel;
  if (i < 65536)        { src = W1;  dst = W1p;   F = 128; Ktot = 512; koff = 0;  rel = i; }
  else if (i < 73728)   { src = W2;  dst = W2p;   F = 64;  Ktot = 128; koff = 0;  rel = i - 65536; }
  else if (i < 90112)   { src = Mc;  dst = Mcp;   F = 256; Ktot = 64;  koff = 0;  rel = i - 73728; }
  else if (i < 94208)   { src = Wsk; dst = Bcatp; F = 64;  Ktot = 320; koff = 0;  rel = i - 90112; }
  else if (i < 110592)  { src = Bvm; dst = Bcatp; F = 64;  Ktot = 320; koff = 64; rel = i - 94208; }
  else if (i < 112640)  { src = Wfc; dst = Wfcp;  F = 32;  Ktot = 64;  koff = 0;  rel = i - 110592; }
  else return;
  int k = rel / F, f = rel - k * F;
  dst[(size_t)f * Ktot + koff + k] = (_Float16)src[rel];
}

// ---- f16 MFMA GEMM: C[M,F] = A[M,K(lda)] @ Bp (+bias) (+BN/ReLU) --------
// A fp32 split on the fly to f16 hi/lo (2 MFMA per product); Bp single f16
// plane [F][K] (transposed). BM=64, 256 threads = 4 waves 2x2.
template <int BN, bool BNR>
__launch_bounds__(256, 2) __global__
void mgemm(const float* __restrict__ A, const _Float16* __restrict__ Bp,
           const float* __restrict__ bias, float* __restrict__ C,
           int M, int K, int lda, int F,
           const float* __restrict__ bn_g, const float* __restrict__ bn_b,
           const float* __restrict__ bn_m, const float* __restrict__ bn_v) {
  constexpr int BM = 64;
  constexpr int BK = 64;
  constexpr int NR = BN / 32;

  __shared__ _Float16 lds[(2 * BM + BN) * BK];
  _Float16* Ah = lds;                // [64][64]
  _Float16* Al = Ah + BM * BK;
  _Float16* Bs = Al + BM * BK;       // [BN][64]

  const int tid = threadIdx.x;
  const int lane = tid & 63;
  const int wid = tid >> 6;
  const int wr = wid >> 1, wc = wid & 1;
  const int l15 = lane & 15, lhi = lane >> 4;
  const int m0 = blockIdx.x * BM;
  const int n0 = blockIdx.y * BN;

  f32x4 acc[2][NR];
#pragma unroll
  for (int mi = 0; mi < 2; ++mi)
#pragma unroll
    for (int ni = 0; ni < NR; ++ni) acc[mi][ni] = (f32x4)0.0f;

  for (int k0 = 0; k0 < K; k0 += BK) {
    // ---- stage A: thread t -> row t>>2, 16-float chunk t&3; f16 hi/lo
    {
      const int r = tid >> 2, ch = tid & 3;
      const int gr = m0 + r;
      float xv[16];
      if (gr < M) {
        const float4* src =
            reinterpret_cast<const float4*>(A + (size_t)gr * lda + k0 + ch * 16);
#pragma unroll
        for (int i = 0; i < 4; ++i) {
          float4 f = src[i];
          xv[i * 4 + 0] = f.x; xv[i * 4 + 1] = f.y;
          xv[i * 4 + 2] = f.z; xv[i * 4 + 3] = f.w;
        }
      } else {
#pragma unroll
        for (int i = 0; i < 16; ++i) xv[i] = 0.0f;
      }
      half8 vh0, vl0, vh1, vl1;
#pragma unroll
      for (int i = 0; i < 8; ++i) {
        _Float16 h = (_Float16)xv[i];
        vh0[i] = h;
        vl0[i] = (_Float16)(xv[i] - (float)h);
      }
#pragma unroll
      for (int i = 0; i < 8; ++i) {
        _Float16 h = (_Float16)xv[8 + i];
        vh1[i] = h;
        vl1[i] = (_Float16)(xv[8 + i] - (float)h);
      }
      const int base = r * 128 + ch * 32;   // bytes (row = 64 f16 = 128B)
      const int sw = (r & 7) << 4;
      *reinterpret_cast<half8*>((char*)Ah + (base ^ sw)) = vh0;
      *reinterpret_cast<half8*>((char*)Ah + ((base + 16) ^ sw)) = vh1;
      *reinterpret_cast<half8*>((char*)Al + (base ^ sw)) = vl0;
      *reinterpret_cast<half8*>((char*)Al + ((base + 16) ^ sw)) = vl1;
    }
    // ---- stage B: BN*8 chunks of 8 f16
    {
#pragma unroll
      for (int it = 0; it < BN / 32; ++it) {
        int id = tid + it * 256;          // 0 .. BN*8-1
        int kc = id & 7;
        int col = id >> 3;
        const uint4v gv = *reinterpret_cast<const uint4v*>(
            Bp + (size_t)(n0 + col) * K + k0 + kc * 8);
        const int base = col * 128 + kc * 16;
        *reinterpret_cast<uint4v*>((char*)Bs + (base ^ ((col & 7) << 4))) = gv;
      }
    }
    __syncthreads();

#pragma unroll
    for (int ks = 0; ks < 2; ++ks) {
      half8 ahf[2], alf[2], bf[NR];
#pragma unroll
      for (int mi = 0; mi < 2; ++mi) {
        int row = wr * 32 + mi * 16 + l15;
        int off = (row * 128 + (ks * 32 + lhi * 8) * 2) ^ ((row & 7) << 4);
        ahf[mi] = *reinterpret_cast<const half8*>((const char*)Ah + off);
        alf[mi] = *reinterpret_cast<const half8*>((const char*)Al + off);
      }
#pragma unroll
      for (int ni = 0; ni < NR; ++ni) {
        int col = wc * (BN / 2) + ni * 16 + l15;
        int off = (col * 128 + (ks * 32 + lhi * 8) * 2) ^ ((col & 7) << 4);
        bf[ni] = *reinterpret_cast<const half8*>((const char*)Bs + off);
      }
#pragma unroll
      for (int mi = 0; mi < 2; ++mi)
#pragma unroll
        for (int ni = 0; ni < NR; ++ni) {
          acc[mi][ni] = __builtin_amdgcn_mfma_f32_16x16x32_f16(
              ahf[mi], bf[ni], acc[mi][ni], 0, 0, 0);
          acc[mi][ni] = __builtin_amdgcn_mfma_f32_16x16x32_f16(
              alf[mi], bf[ni], acc[mi][ni], 0, 0, 0);
        }
    }
    __syncthreads();
  }

  // epilogue: C/D layout col=lane&15, row=(lane>>4)*4+reg
#pragma unroll
  for (int mi = 0; mi < 2; ++mi) {
#pragma unroll
    for (int ni = 0; ni < NR; ++ni) {
      const int col = n0 + wc * (BN / 2) + ni * 16 + l15;
      const float bv = bias ? bias[col] : 0.0f;
      float bns = 0.f, bnb = 0.f, bnm = 0.f;
      if (BNR) {
        bns = bn_g[col] * rsqrtf(bn_v[col] + EPS);
        bnb = bn_b[col];
        bnm = bn_m[col];
      }
#pragma unroll
      for (int r4 = 0; r4 < 4; ++r4) {
        const int row = m0 + wr * 32 + mi * 16 + lhi * 4 + r4;
        if (row < M) {
          float vout = acc[mi][ni][r4] + bv;
          if (BNR) {
            vout = (vout - bnm) * bns + bnb;
            vout = vout > 0.f ? vout : 0.f;
          }
          C[(size_t)row * F + col] = vout;
        }
      }
    }
  }
}

// ---- GCN propagate (CSR gather) + BN + ReLU, wave per dst (perm) --------
template <int F>
__launch_bounds__(256) __global__
void k_gcn(const int* __restrict__ ro, const int* __restrict__ csr_src,
           const float* __restrict__ csr_nrm, const int* __restrict__ perm,
           const float* __restrict__ h, const float* __restrict__ dinv,
           const float* __restrict__ bias, const float* __restrict__ g,
           const float* __restrict__ be, const float* __restrict__ m,
           const float* __restrict__ v, float* __restrict__ out, int ldo) {
  const int idx = blockIdx.x * 4 + (threadIdx.x >> 6);
  const int lane = threadIdx.x & 63;
  if (idx >= NN) return;
  const int wid = perm[idx];
  const float di = dinv[wid];
  const float di2 = di * di;
  const int p0 = ro[wid], p1 = ro[wid + 1];

  if (F == 128) {
    float2 a0 = reinterpret_cast<const float2*>(h + (size_t)wid * 128)[lane];
    a0.x *= di2; a0.y *= di2;
    float2 a1 = make_float2(0.f, 0.f), a2 = make_float2(0.f, 0.f),
           a3 = make_float2(0.f, 0.f);
    int p = p0;
    for (; p + 4 <= p1; p += 4) {
      int s0 = csr_src[p], s1 = csr_src[p + 1], s2 = csr_src[p + 2],
          s3 = csr_src[p + 3];
      float w0 = csr_nrm[p], w1 = csr_nrm[p + 1], w2 = csr_nrm[p + 2],
            w3 = csr_nrm[p + 3];
      float2 h0 = reinterpret_cast<const float2*>(h + (size_t)s0 * 128)[lane];
      float2 h1 = reinterpret_cast<const float2*>(h + (size_t)s1 * 128)[lane];
      float2 h2 = reinterpret_cast<const float2*>(h + (size_t)s2 * 128)[lane];
      float2 h3 = reinterpret_cast<const float2*>(h + (size_t)s3 * 128)[lane];
      a0.x += w0 * h0.x; a0.y += w0 * h0.y;
      a1.x += w1 * h1.x; a1.y += w1 * h1.y;
      a2.x += w2 * h2.x; a2.y += w2 * h2.y;
      a3.x += w3 * h3.x; a3.y += w3 * h3.y;
    }
    for (; p < p1; ++p) {
      int s = csr_src[p];
      float w = csr_nrm[p];
      float2 hv = reinterpret_cast<const float2*>(h + (size_t)s * 128)[lane];
      a1.x += w * hv.x; a1.y += w * hv.y;
    }
    float2 a;
    a.x = (a0.x + a1.x) + (a2.x + a3.x);
    a.y = (a0.y + a1.y) + (a2.y + a3.y);
    float2 gg = reinterpret_cast<const float2*>(g)[lane];
    float2 bb = reinterpret_cast<const float2*>(be)[lane];
    float2 mm = reinterpret_cast<const float2*>(m)[lane];
    float2 vv = reinterpret_cast<const float2*>(v)[lane];
    float2 bi = bias ? reinterpret_cast<const float2*>(bias)[lane]
                     : make_float2(0.f, 0.f);
    float s0 = gg.x * rsqrtf(vv.x + EPS);
    float s1 = gg.y * rsqrtf(vv.y + EPS);
    float y0 = (a.x + bi.x - mm.x) * s0 + bb.x;
    float y1 = (a.y + bi.y - mm.y) * s1 + bb.y;
    float2 o;
    o.x = y0 > 0.f ? y0 : 0.f;
    o.y = y1 > 0.f ? y1 : 0.f;
    reinterpret_cast<float2*>(out + (size_t)wid * ldo)[lane] = o;
  } else {
    float a0 = h[(size_t)wid * F + lane] * di2;
    float a1 = 0.f, a2 = 0.f, a3 = 0.f;
    int p = p0;
    for (; p + 4 <= p1; p += 4) {
      int s0 = csr_src[p], s1 = csr_src[p + 1], s2 = csr_src[p + 2],
          s3 = csr_src[p + 3];
      float w0 = csr_nrm[p], w1 = csr_nrm[p + 1], w2 = csr_nrm[p + 2],
            w3 = csr_nrm[p + 3];
      a0 += w0 * h[(size_t)s0 * F + lane];
      a1 += w1 * h[(size_t)s1 * F + lane];
      a2 += w2 * h[(size_t)s2 * F + lane];
      a3 += w3 * h[(size_t)s3 * F + lane];
    }
    for (; p < p1; ++p) a1 += csr_nrm[p] * h[(size_t)csr_src[p] * F + lane];
    float a = (a0 + a1) + (a2 + a3);
    float sc = g[lane] * rsqrtf(v[lane] + EPS);
    float bi = bias ? bias[lane] : 0.f;
    float y = (a + bi - m[lane]) * sc + be[lane];
    out[(size_t)wid * ldo + lane] = y > 0.f ? y : 0.f;
  }
}

// ---- fused edge-softmax attention: 16 lanes/dst, 4 dsts/wave ------------
// z = zu cols 0..63 (stride 320); u written to zu cols 64..319.
__launch_bounds__(256) __global__
void k_attn(const int* __restrict__ ro, const int* __restrict__ csr_src,
            const int* __restrict__ perm, float* zu,
            const float* __restrict__ qpp) {
  const int wave = blockIdx.x * 4 + (threadIdx.x >> 6);
  const int lane = threadIdx.x & 63;
  const int g = lane >> 4;
  const int t = lane & 15;
  const bool bit3 = (t & 8) != 0, bit2 = (t & 4) != 0;

  const int idx = wave * 4 + g;
  const bool valid = idx < NN;
  const int dst = perm[valid ? idx : 0];

  float4 q[4];
#pragma unroll
  for (int h = 0; h < 4; ++h)
    q[h] = *reinterpret_cast<const float4*>(qpp + (size_t)dst * 256 + h * 64 + t * 4);

  float4 ua[4];
  float den[4];
#pragma unroll
  for (int h = 0; h < 4; ++h) {
    ua[h] = make_float4(0.f, 0.f, 0.f, 0.f);
    den[h] = 0.f;
  }

  int p = valid ? ro[dst] : 0;
  int p1 = valid ? ro[dst + 1] : 0;

  while (__ballot(p < p1)) {
    const bool act = p < p1;
    const int pc = act ? p : 0;
    const int s = csr_src[pc];
    const float4 zv = *reinterpret_cast<const float4*>(zu + (size_t)s * 320 + t * 4);

    float p0 = q[0].x * zv.x + q[0].y * zv.y + q[0].z * zv.z + q[0].w * zv.w;
    float p1h = q[1].x * zv.x + q[1].y * zv.y + q[1].z * zv.z + q[1].w * zv.w;
    float p2 = q[2].x * zv.x + q[2].y * zv.y + q[2].z * zv.z + q[2].w * zv.w;
    float p3 = q[3].x * zv.x + q[3].y * zv.y + q[3].z * zv.z + q[3].w * zv.w;

    float send1 = bit3 ? p0 : p2;
    float recv1 = __shfl_xor(send1, 8);
    float a0 = (bit3 ? p2 : p0) + recv1;
    float send2 = bit3 ? p1h : p3;
    float recv2 = __shfl_xor(send2, 8);
    float a1 = (bit3 ? p3 : p1h) + recv2;
    float send3 = bit2 ? a0 : a1;
    float recv3 = __shfl_xor(send3, 4);
    float b = (bit2 ? a1 : a0) + recv3;
    b += __shfl_xor(b, 2);
    b += __shfl_xor(b, 1);

    float r4 = __shfl_xor(b, 4);
    float r8 = __shfl_xor(b, 8);
    float r84 = __shfl_xor(r4, 8);
    float sc0 = bit3 ? (bit2 ? r84 : r8) : (bit2 ? r4 : b);
    float sc1 = bit3 ? (bit2 ? r8 : r84) : (bit2 ? b : r4);
    float sc2 = bit3 ? (bit2 ? r4 : b) : (bit2 ? r84 : r8);
    float sc3 = bit3 ? (bit2 ? b : r4) : (bit2 ? r8 : r84);

    float e0 = act ? __expf(fminf(sc0, 60.f)) : 0.f;
    float e1 = act ? __expf(fminf(sc1, 60.f)) : 0.f;
    float e2 = act ? __expf(fminf(sc2, 60.f)) : 0.f;
    float e3 = act ? __expf(fminf(sc3, 60.f)) : 0.f;

    den[0] += e0; den[1] += e1; den[2] += e2; den[3] += e3;
    ua[0].x += e0 * zv.x; ua[0].y += e0 * zv.y; ua[0].z += e0 * zv.z; ua[0].w += e0 * zv.w;
    ua[1].x += e1 * zv.x; ua[1].y += e1 * zv.y; ua[1].z += e1 * zv.z; ua[1].w += e1 * zv.w;
    ua[2].x += e2 * zv.x; ua[2].y += e2 * zv.y; ua[2].z += e2 * zv.z; ua[2].w += e2 * zv.w;
    ua[3].x += e3 * zv.x; ua[3].y += e3 * zv.y; ua[3].z += e3 * zv.z; ua[3].w += e3 * zv.w;
    ++p;
  }

  if (valid) {
#pragma unroll
    for (int h = 0; h < 4; ++h) {
      float inv = 1.0f / (den[h] + 1e-16f);
      float4 o;
      o.x = ua[h].x * inv; o.y = ua[h].y * inv;
      o.z = ua[h].z * inv; o.w = ua[h].w * inv;
      *reinterpret_cast<float4*>(zu + (size_t)dst * 320 + 64 + h * 64 + t * 4) = o;
    }
  }
}

}  // namespace

extern "C" void kernel_launch(void* const* d_in, const int* in_sizes, int n_in,
                              void* d_out, int out_size, void* d_ws, size_t ws_size,
                              hipStream_t stream) {
  const float* x   = (const float*)d_in[0];
  const int*   ei  = (const int*)d_in[1];
  const float* ew  = (const float*)d_in[2];
  const float* W1  = (const float*)d_in[3];
  const float* b1  = (const float*)d_in[4];
  const float* g1  = (const float*)d_in[5];
  const float* be1 = (const float*)d_in[6];
  const float* m1  = (const float*)d_in[7];
  const float* v1  = (const float*)d_in[8];
  const float* W2  = (const float*)d_in[9];
  const float* b2  = (const float*)d_in[10];
  const float* g2  = (const float*)d_in[11];
  const float* be2 = (const float*)d_in[12];
  const float* m2  = (const float*)d_in[13];
  const float* v2  = (const float*)d_in[14];
  const float* Wq  = (const float*)d_in[15];
  const float* bq  = (const float*)d_in[16];
  const float* Wk  = (const float*)d_in[17];
  const float* Wv  = (const float*)d_in[19];
  const float* bv  = (const float*)d_in[20];
  const float* Wsk = (const float*)d_in[21];
  const float* bsk = (const float*)d_in[22];
  const float* gt  = (const float*)d_in[23];
  const float* bet = (const float*)d_in[24];
  const float* mt  = (const float*)d_in[25];
  const float* vt  = (const float*)d_in[26];
  const float* Wfc = (const float*)d_in[27];
  const float* bfc = (const float*)d_in[28];

  constexpr int NP = 50048;  // padded N (multiple of 64)
  float* ws = (float*)d_ws;
  float* dinv    = ws;                           // NP
  int*   cnt     = (int*)(dinv + NP);            // NP
  int*   cur     = cnt + NP;                     // NP
  int*   ro      = cur + NP;                     // NP (N+1 used)
  int*   perm    = ro + NP;                      // NP
  int*   csr_src = perm + NP;                    // E
  float* csr_nrm = (float*)(csr_src + EE);       // E
  int*   blkhist = (int*)(csr_nrm + EE);         // PBLK*64
  int*   blkoff  = blkhist + PBLK * 64;          // PBLK*64
  float* h1      = (float*)(blkoff + PBLK * 64); // N*128
  float* a1      = h1 + (size_t)NN * GH;         // N*128
  float* h2      = a1 + (size_t)NN * GH;         // N*64
  float* zu      = h2 + (size_t)NN * GO;         // N*320
  float* qpp     = zu + (size_t)NN * 320;        // N*256
  float* agg     = qpp + (size_t)NN * 256;       // N*64
  float* Mc      = agg + (size_t)NN * GO;        // 64*256
  float* cvec    = Mc + 64 * 256;                // 256
  float* Bvm     = cvec + 256;                   // 256*64
  float* bcomb   = Bvm + 256 * 64;               // 64
  _Float16* W1p  = (_Float16*)(bcomb + 64);      // 512*128
  _Float16* W2p  = W1p + 512 * 128;              // 128*64
  _Float16* Mcp  = W2p + 128 * 64;               // 64*256
  _Float16* Bcatp= Mcp + 64 * 256;               // 320*64
  _Float16* Wfcp = Bcatp + 320 * 64;             // 64*32

  const int tb = 256;
  const int gM = cdiv(NN, 64);  // 782 row-blocks

  // graph prep + CSR + contention-free degree sort
  k_init0<<<cdiv(NN, tb), tb, 0, stream>>>(dinv, cnt, cur);
  k_edge1<<<cdiv(EE, tb), tb, 0, stream>>>(ei, ew, dinv, cnt);
  k_dinv<<<cdiv(NN, tb), tb, 0, stream>>>(dinv);
  k_scan<<<1, 1024, 0, stream>>>(cnt, ro);
  k_fill<<<cdiv(EE, tb), tb, 0, stream>>>(ei, ew, dinv, ro, cur, csr_src, csr_nrm);
  k_bhist<<<PBLK, 256, 0, stream>>>(cnt, blkhist);
  k_boff<<<1, 64, 0, stream>>>(blkhist, blkoff);
  k_perm2<<<PBLK, 256, 0, stream>>>(cnt, blkoff, perm);

  // attention weight precompute + single f16 convert pass
  k_prep_mc<<<64, 256, 0, stream>>>(Wq, Wk, bq, Mc, cvec);
  k_prep_bv<<<64, 256, 0, stream>>>(Wv, bv, bsk, Bvm, bcomb);
  k_cvt<<<cdiv(112640, tb), tb, 0, stream>>>(W1, W2, Mc, Wsk, Bvm, Wfc,
                                             W1p, W2p, Mcp, Bcatp, Wfcp);

  // GCN layer 1: h1 = x @ W1 ; propagate+BN+ReLU -> a1
  mgemm<128, false><<<dim3(gM, 1), 256, 0, stream>>>(
      x, W1p, nullptr, h1, NN, CIN, CIN, GH, nullptr, nullptr, nullptr, nullptr);
  k_gcn<GH><<<cdiv(NN, 4), 256, 0, stream>>>(ro, csr_src, csr_nrm, perm, h1, dinv,
                                             b1, g1, be1, m1, v1, a1, GH);
  // GCN layer 2: h2 = a1 @ W2 ; propagate+BN+ReLU -> zu[:, 0:64]
  mgemm<64, false><<<dim3(gM, 1), 256, 0, stream>>>(
      a1, W2p, nullptr, h2, NN, GH, GH, GO, nullptr, nullptr, nullptr, nullptr);
  k_gcn<GO><<<cdiv(NN, 4), 256, 0, stream>>>(ro, csr_src, csr_nrm, perm, h2, dinv,
                                             b2, g2, be2, m2, v2, zu, 320);

  // TransformerConv: qpp = z @ Mc + cvec ; fused edge softmax -> zu[:, 64:320]
  mgemm<128, false><<<dim3(gM, 2), 256, 0, stream>>>(
      zu, Mcp, cvec, qpp, NN, GO, 320, 256, nullptr, nullptr, nullptr, nullptr);
  k_attn<<<cdiv(NN, 16), 256, 0, stream>>>(ro, csr_src, perm, zu, qpp);

  // agg = [z|u] @ [Wsk;Bv] + bcomb ; BN_t + ReLU fused
  mgemm<64, true><<<dim3(gM, 1), 256, 0, stream>>>(
      zu, Bcatp, bcomb, agg, NN, 320, 320, GO, gt, bet, mt, vt);

  // final linear
  mgemm<32, false><<<dim3(gM, 1), 256, 0, stream>>>(
      agg, Wfcp, bfc, (float*)d_out, NN, GO, GO, COUT,
      nullptr, nullptr, nullptr, nullptr);
}